// Round 2
// baseline (140.245 us; speedup 1.0000x reference)
//
#include <hip/hip_runtime.h>

#define BB 8
#define LL 1024
#define DD 512
#define HDIM 4096
#define EPS_LN 1e-5f
#define NB 512
#define NT 512
#define POISON_I ((int)0xAAAAAAAAu)
#define ARRIVALS 64

// R11: fused kernel, restructured for OVERLAP, sync pattern unchanged.
//
// R10 evidence: removing both barriers AND all atomics (3-kernel split)
// changed the kernel-side time by only ~+3 us => sync costs ~2-3 us, not
// ~20. The slack is in the phases: interior ~31 us vs ~9.5 us phase
// roofline (48 MB mandatory traffic). Cause: 256x1024 = 1 block/CU, so
// every barrier wait and phase-boundary HBM ramp idles the CU, and phase
// B's 16 MB weight stream starts cold after barrier1.
//
// Changes vs the 117.6-us R9 kernel:
//  1. 512 blocks x 512 threads = 2 blocks/CU. Block bi: b=bi>>6 (batch),
//     j=bi&63 (16-row slice / 64-col chunk). Co-resident blocks pipeline
//     independently; barrier stalls of one hide under the other's work.
//     All reductions now use all 512 threads (no idle half-block).
//  2. wv prefetch: 48 of 64 column values per thread loaded into
//     registers DURING phase A (weights depend on nothing) — ~12 MB of
//     weight traffic overlaps the x-read + barrier1 wait. g/beta/fcb
//     prefetched before barrier2. VGPR ~105 < 128 cap (16 waves/CU).
//
// Sync: IDENTICAL per-batch counter barrier proven R2-R9 (vmcnt(0) drain
// -> one RELAXED agent-scope arrival per block -> thread-0 spin). Now 64
// arrivals per counter. Cross-block data (xs,u) written ONLY via
// device-scope atomicAdd (MALL); readers first-touch after observing the
// count (control dep). Poison 0xAAAAAAAA == -3.03e-13f (~0) for the
// atomicAdd targets; counters start at POISON_I.
//
// XCD locality: chunk j is read by blocks {b*64+j}, all == j (mod 8) ->
// same XCD under round-robin -> 8 j's x 256 KB (wv+fcw) = 2 MB per L2.
// Performance-only assumption.

__device__ __forceinline__ void batch_bar(int* cnt) {
    asm volatile("s_waitcnt vmcnt(0)" ::: "memory");  // every wave drains
    __syncthreads();
    if (threadIdx.x == 0) {
        __hip_atomic_fetch_add(cnt, 1, __ATOMIC_RELAXED,
                               __HIP_MEMORY_SCOPE_AGENT);
        while (__hip_atomic_load(cnt, __ATOMIC_RELAXED,
                                 __HIP_MEMORY_SCOPE_AGENT) !=
               POISON_I + ARRIVALS)
            __builtin_amdgcn_s_sleep(1);
        asm volatile("" ::: "memory");
    }
    __syncthreads();
}

__global__ __launch_bounds__(NT, 4) void mha_fused(
    const float* __restrict__ x,
    const float* __restrict__ wv,
    const float* __restrict__ bv,
    const float* __restrict__ fcw,
    const float* __restrict__ fcb,
    const float* __restrict__ g,
    const float* __restrict__ beta,
    float* __restrict__ out,
    float* __restrict__ xs,       // ws, poison-seeded (~0), atomic target
    float* __restrict__ u,        // ws, poison-seeded (~0), atomic target
    int* __restrict__ bar)        // ws, 16 padded counter lines, poison
{
    __shared__ float redA[8][DD];    // 16 KB (phase A)
    __shared__ float xs_b[DD];       // 2 KB  (phase B)
    __shared__ float Tpart[8][64];   // 2 KB  (phase B)
    __shared__ float T_l[64];        // 256 B (phase B)
    __shared__ float uf[DD];         // 2 KB  (phase C)

    const int tid = threadIdx.x;
    const int bi  = blockIdx.x;      // 0..511
    const int b   = bi >> 6;         // batch
    const int j   = bi & 63;         // 16-row slice / 64-col chunk

    const int dv   = tid & 63;       // lane
    const int rowg = tid >> 6;       // wave id 0..7
    // phase-B mapping collapses onto the same split:
    const int cI = dv;               // column within 64-col chunk
    const int kg = rowg;             // k-group (64 k's each)

    float4 xa0, xa1, xb0, xb1;       // x kept in regs A -> C
    float  wpre[48];                 // wv prefetch (held across barrier1)

    // ---------------- Phase A + weight prefetch ----------------
    const float* wcol = wv + (size_t)(j * 64) + cI;
    {
        const float* basep = x + ((size_t)(bi * 16 + rowg * 2)) * DD + dv * 8;
        xa0 = *(const float4*)(basep);
        xa1 = *(const float4*)(basep + 4);
        xb0 = *(const float4*)(basep + DD);
        xb1 = *(const float4*)(basep + DD + 4);

        // wv does not depend on xs: fetch 48/64 of this thread's column
        // values now, overlapping the x read, LDS reduce, and barrier1.
#pragma unroll
        for (int i = 0; i < 48; ++i)
            wpre[i] = wcol[(size_t)(kg * 64 + i) * HDIM];

        float4* dst = (float4*)&redA[rowg][dv * 8];
        dst[0] = make_float4(xa0.x + xb0.x, xa0.y + xb0.y,
                             xa0.z + xb0.z, xa0.w + xb0.w);
        dst[1] = make_float4(xa1.x + xb1.x, xa1.y + xb1.y,
                             xa1.z + xb1.z, xa1.w + xb1.w);
        __syncthreads();

        float s = 0.f;                      // all 512 threads participate
#pragma unroll
        for (int gg = 0; gg < 8; ++gg) s += redA[gg][tid];
        atomicAdd(&xs[b * DD + tid], s);    // device-scope -> MALL
    }

    batch_bar(bar + b * 32);         // xs[b] complete (64 arrivals)

    // ---- Phase B: T[b, j*64..] from wv columns + u[b] partial via fcw ----
    {
        xs_b[tid] = xs[b * DD + tid];       // first touch after barrier
        __syncthreads();

        float t = 0.f;
#pragma unroll
        for (int i = 0; i < 48; ++i)        // prefetched part: FMA only
            t += xs_b[kg * 64 + i] * wpre[i];
#pragma unroll
        for (int i = 48; i < 64; ++i)       // streamed tail
            t += xs_b[kg * 64 + i] * wcol[(size_t)(kg * 64 + i) * HDIM];
        Tpart[kg][cI] = t;
        __syncthreads();

        if (tid < 64) {
            float s = 0.f;
#pragma unroll
            for (int q = 0; q < 8; ++q) s += Tpart[q][tid];
            T_l[tid] = s + 1024.f * bv[j * 64 + tid];
        }
        __syncthreads();

        float a = 0.f;                      // u partial: all 512 threads
        const float* frow = fcw + (size_t)(j * 64) * DD + tid;
#pragma unroll 8
        for (int c = 0; c < 64; ++c)
            a += T_l[c] * frow[(size_t)c * DD];
        atomicAdd(&u[b * DD + tid], a);     // device-scope -> MALL
    }

    // prefetch phase-C constants before the drain (L3-hot, tiny)
    float4 g0  = *(const float4*)(g + dv * 8);
    float4 g1  = *(const float4*)(g + dv * 8 + 4);
    float4 bt0 = *(const float4*)(beta + dv * 8);
    float4 bt1 = *(const float4*)(beta + dv * 8 + 4);
    float  fpre = fcb[tid];

    batch_bar(bar + (8 + b) * 32);   // u[b] complete (64 arrivals)

    // ---------- Phase C: y = LN(x + u + fc_b)*g + beta ----------
    {
        uf[tid] = u[b * DD + tid] + fpre;   // first touch after barrier
        __syncthreads();

        float4 uq0 = *(const float4*)(uf + dv * 8);
        float4 uq1 = *(const float4*)(uf + dv * 8 + 4);

#pragma unroll
        for (int it = 0; it < 2; ++it) {
            const int row = bi * 16 + rowg * 2 + it;
            const size_t off = (size_t)row * DD + dv * 8;
            float4 x0 = (it == 0) ? xa0 : xb0;   // registers, no reload
            float4 x1 = (it == 0) ? xa1 : xb1;

            float y[8];
            y[0] = x0.x + uq0.x;  y[1] = x0.y + uq0.y;
            y[2] = x0.z + uq0.z;  y[3] = x0.w + uq0.w;
            y[4] = x1.x + uq1.x;  y[5] = x1.y + uq1.y;
            y[6] = x1.z + uq1.z;  y[7] = x1.w + uq1.w;

            float s1 = 0.f, ss = 0.f;
#pragma unroll
            for (int i = 0; i < 8; ++i) { s1 += y[i]; ss += y[i] * y[i]; }
#pragma unroll
            for (int m = 1; m < 64; m <<= 1) {
                s1 += __shfl_xor(s1, m, 64);
                ss += __shfl_xor(ss, m, 64);
            }
            const float mean = s1 * (1.f / 512.f);
            const float var  = ss * (1.f / 512.f) - mean * mean;
            const float rstd = rsqrtf(var + EPS_LN);

            float4 o0, o1;
            o0.x = (y[0] - mean) * rstd * g0.x + bt0.x;
            o0.y = (y[1] - mean) * rstd * g0.y + bt0.y;
            o0.z = (y[2] - mean) * rstd * g0.z + bt0.z;
            o0.w = (y[3] - mean) * rstd * g0.w + bt0.w;
            o1.x = (y[4] - mean) * rstd * g1.x + bt1.x;
            o1.y = (y[5] - mean) * rstd * g1.y + bt1.y;
            o1.z = (y[6] - mean) * rstd * g1.z + bt1.z;
            o1.w = (y[7] - mean) * rstd * g1.w + bt1.w;
            *(float4*)(out + off)     = o0;
            *(float4*)(out + off + 4) = o1;
        }
    }
}

extern "C" void kernel_launch(void* const* d_in, const int* in_sizes, int n_in,
                              void* d_out, int out_size, void* d_ws, size_t ws_size,
                              hipStream_t stream) {
    // setup_inputs order:
    // 0 input, 1 wq, 2 bq, 3 wk, 4 bk, 5 wv, 6 bv, 7 score_w, 8 score_b,
    // 9 fc_w, 10 fc_b, 11 ln_g, 12 ln_b
    // (wq/bq/wk/bk/score_* are dead: softmax over a size-1 axis == 1.)
    const float* x   = (const float*)d_in[0];
    const float* wv  = (const float*)d_in[5];
    const float* bv  = (const float*)d_in[6];
    const float* fcw = (const float*)d_in[9];
    const float* fcb = (const float*)d_in[10];
    const float* lng = (const float*)d_in[11];
    const float* lnb = (const float*)d_in[12];

    float* xs  = (float*)d_ws;                      // 16 KB @ 0
    int*   bar = (int*)((char*)d_ws + 16 * 1024);   // 16 counter lines
    float* u   = (float*)((char*)d_ws + 32 * 1024); // 16 KB final u
    float* out = (float*)d_out;

    mha_fused<<<NB, NT, 0, stream>>>(x, wv, bv, fcw, fcb, lng, lnb,
                                     out, xs, u, bar);
}

// Round 3
// 127.686 us; speedup vs baseline: 1.0984x; 1.0984x over previous
//
#include <hip/hip_runtime.h>

#define BB 8
#define LL 1024
#define DD 512
#define HDIM 4096
#define EPS_LN 1e-5f
#define NB 512
#define NT 1024
#define POISON_I ((int)0xAAAAAAAAu)
#define ARRIVALS 64

// R12: ONE lever vs the 117.6-us R9 kernel — 32 waves/CU (was 16).
//
// Post-mortem R11: wpre[48] register prefetch SPILLED (VGPR_Count=64,
// WRITE_SIZE 36.9MB vs 16.05 expected => ~20MB scratch writes) -> kernel
// 31->46us. Lesson: no big per-thread arrays; keep live state < 64 VGPR.
// Post-mortem R10: removing barriers+atomics entirely was neutral =>
// sync costs ~2-3us, not the bottleneck.
// Remaining theory: R9 and R11 both ran 16 waves/CU; phases stream 48MB
// at ~1.5-3 TB/s effective with VALUBusy ~7% => under-subscription.
// The harness fills (256-wave pure streams) hit 6.1 TB/s on this chip.
//
// R12: 512 blocks x 1024 threads = 2 blocks/CU x 16 waves = 32 waves/CU.
//   block bi: b = bi>>6 (batch), j = bi&63 (16-row slice / 64-col chunk).
//   __launch_bounds__(1024, 8) caps VGPR at 64; per-thread state kept
//   ~45 (x row segment 8 floats; g/beta loaded at use; no prefetch
//   arrays; streaming loops unroll 8 only).
//   LDS 40.3 KB <= 80 KB/block for 2-block residency.
//
// Sync: IDENTICAL per-batch counter barrier proven R2-R9 (vmcnt(0) drain
// -> one RELAXED agent-scope arrival per block -> thread-0 spin), now 64
// arrivals. Cross-block data (xs,u) written ONLY via device-scope
// atomicAdd (MALL); readers first-touch after observing the count
// (control dep). Poison 0xAAAAAAAA == -3.03e-13f (~0) for atomicAdd
// targets; counters start at POISON_I.
//
// XCD locality: chunk j read by blocks {b*64+j, b=0..7}, all == j (mod 8)
// -> same XCD under round-robin -> 8 chunks x 256 KB (wv+fcw) = 2 MB per
// 4 MB L2. Performance-only assumption.
//
// Spill sentinels for the post-mortem: WRITE_SIZE must be ~16.05 MB and
// VGPR_Count <= 64 with OccupancyPercent > 50.

__device__ __forceinline__ void batch_bar(int* cnt) {
    asm volatile("s_waitcnt vmcnt(0)" ::: "memory");  // every wave drains
    __syncthreads();
    if (threadIdx.x == 0) {
        __hip_atomic_fetch_add(cnt, 1, __ATOMIC_RELAXED,
                               __HIP_MEMORY_SCOPE_AGENT);
        while (__hip_atomic_load(cnt, __ATOMIC_RELAXED,
                                 __HIP_MEMORY_SCOPE_AGENT) !=
               POISON_I + ARRIVALS)
            __builtin_amdgcn_s_sleep(1);
        asm volatile("" ::: "memory");
    }
    __syncthreads();
}

__global__ __launch_bounds__(NT, 8) void mha_fused(
    const float* __restrict__ x,
    const float* __restrict__ wv,
    const float* __restrict__ bv,
    const float* __restrict__ fcw,
    const float* __restrict__ fcb,
    const float* __restrict__ g,
    const float* __restrict__ beta,
    float* __restrict__ out,
    float* __restrict__ xs,       // ws, poison-seeded (~0), atomic target
    float* __restrict__ u,        // ws, poison-seeded (~0), atomic target
    int* __restrict__ bar)        // ws, 16 padded counter lines, poison
{
    __shared__ float redA[16][DD];   // 32 KB   (phase A)
    __shared__ float xs_b[DD];       // 2 KB    (phase B)
    __shared__ float Tpart[16][64];  // 4 KB    (phase B)
    __shared__ float T_l[64];        // 256 B   (phase B)
    __shared__ float uf[DD];         // 2 KB    (phase C)

    const int tid = threadIdx.x;
    const int bi  = blockIdx.x;      // 0..511
    const int b   = bi >> 6;         // batch
    const int j   = bi & 63;         // 16-row slice / 64-col chunk

    const int dv  = tid & 63;        // lane
    const int wid = tid >> 6;        // wave 0..15

    float4 xr0, xr1;                 // this thread's 8 x-values, A -> C

    // ---------------- Phase A: xs[b] += column-sums of my 16 rows ----------
    {
        const float* basep = x + ((size_t)(bi * 16 + wid)) * DD + dv * 8;
        xr0 = *(const float4*)(basep);
        xr1 = *(const float4*)(basep + 4);

        float4* dst = (float4*)&redA[wid][dv * 8];
        dst[0] = xr0;
        dst[1] = xr1;
        __syncthreads();

        if (tid < DD) {
            float s = 0.f;
#pragma unroll
            for (int gg = 0; gg < 16; ++gg) s += redA[gg][tid];
            atomicAdd(&xs[b * DD + tid], s);   // device-scope -> MALL
        }
    }

    batch_bar(bar + b * 32);         // xs[b] complete (64 arrivals)

    // ---- Phase B: T[b, j*64..] from wv columns + u[b] partial via fcw ----
    {
        if (tid < DD) xs_b[tid] = xs[b * DD + tid];   // first touch
        __syncthreads();

        const int cI = dv;           // column within 64-col chunk
        const int kg = wid;          // k-group: 16 groups x 32 k's
        float t = 0.f;
        const float* wcol = wv + (size_t)(j * 64) + cI;
#pragma unroll 8
        for (int i = 0; i < 32; ++i) {
            const int k = kg * 32 + i;
            t += xs_b[k] * wcol[(size_t)k * HDIM];
        }
        Tpart[kg][cI] = t;
        __syncthreads();

        if (tid < 64) {
            float s = 0.f;
#pragma unroll
            for (int q = 0; q < 16; ++q) s += Tpart[q][tid];
            T_l[tid] = s + 1024.f * bv[j * 64 + tid];
        }
        __syncthreads();

        const int dd = tid & 511;
        const int ch = tid >> 9;     // 0/1: 32 c's each
        float a = 0.f;
        const float* frow = fcw + (size_t)(j * 64 + ch * 32) * DD + dd;
#pragma unroll 8
        for (int i = 0; i < 32; ++i)
            a += T_l[ch * 32 + i] * frow[(size_t)i * DD];
        atomicAdd(&u[b * DD + dd], a);   // device-scope -> MALL
    }

    batch_bar(bar + (8 + b) * 32);   // u[b] complete (64 arrivals)

    // ---------- Phase C: y = LN(x + u + fc_b)*g + beta ----------
    {
        if (tid < DD) uf[tid] = u[b * DD + tid] + fcb[tid];  // first touch
        __syncthreads();

        float4 uq0 = *(const float4*)(uf + dv * 8);
        float4 uq1 = *(const float4*)(uf + dv * 8 + 4);

        const int row = bi * 16 + wid;
        const size_t off = (size_t)row * DD + dv * 8;

        float y[8];
        y[0] = xr0.x + uq0.x;  y[1] = xr0.y + uq0.y;
        y[2] = xr0.z + uq0.z;  y[3] = xr0.w + uq0.w;
        y[4] = xr1.x + uq1.x;  y[5] = xr1.y + uq1.y;
        y[6] = xr1.z + uq1.z;  y[7] = xr1.w + uq1.w;

        float s1 = 0.f, ss = 0.f;
#pragma unroll
        for (int i = 0; i < 8; ++i) { s1 += y[i]; ss += y[i] * y[i]; }
#pragma unroll
        for (int m = 1; m < 64; m <<= 1) {
            s1 += __shfl_xor(s1, m, 64);
            ss += __shfl_xor(ss, m, 64);
        }
        const float mean = s1 * (1.f / 512.f);
        const float var  = ss * (1.f / 512.f) - mean * mean;
        const float rstd = rsqrtf(var + EPS_LN);

        // g/beta loaded at use (L2/L3-hot, 16 KB per block) — no long-lived
        // registers held across barriers.
        float4 g0  = *(const float4*)(g + dv * 8);
        float4 g1  = *(const float4*)(g + dv * 8 + 4);
        float4 bt0 = *(const float4*)(beta + dv * 8);
        float4 bt1 = *(const float4*)(beta + dv * 8 + 4);

        float4 o0, o1;
        o0.x = (y[0] - mean) * rstd * g0.x + bt0.x;
        o0.y = (y[1] - mean) * rstd * g0.y + bt0.y;
        o0.z = (y[2] - mean) * rstd * g0.z + bt0.z;
        o0.w = (y[3] - mean) * rstd * g0.w + bt0.w;
        o1.x = (y[4] - mean) * rstd * g1.x + bt1.x;
        o1.y = (y[5] - mean) * rstd * g1.y + bt1.y;
        o1.z = (y[6] - mean) * rstd * g1.z + bt1.z;
        o1.w = (y[7] - mean) * rstd * g1.w + bt1.w;
        *(float4*)(out + off)     = o0;
        *(float4*)(out + off + 4) = o1;
    }
}

extern "C" void kernel_launch(void* const* d_in, const int* in_sizes, int n_in,
                              void* d_out, int out_size, void* d_ws, size_t ws_size,
                              hipStream_t stream) {
    // setup_inputs order:
    // 0 input, 1 wq, 2 bq, 3 wk, 4 bk, 5 wv, 6 bv, 7 score_w, 8 score_b,
    // 9 fc_w, 10 fc_b, 11 ln_g, 12 ln_b
    // (wq/bq/wk/bk/score_* are dead: softmax over a size-1 axis == 1.)
    const float* x   = (const float*)d_in[0];
    const float* wv  = (const float*)d_in[5];
    const float* bv  = (const float*)d_in[6];
    const float* fcw = (const float*)d_in[9];
    const float* fcb = (const float*)d_in[10];
    const float* lng = (const float*)d_in[11];
    const float* lnb = (const float*)d_in[12];

    float* xs  = (float*)d_ws;                      // 16 KB @ 0
    int*   bar = (int*)((char*)d_ws + 16 * 1024);   // 16 counter lines
    float* u   = (float*)((char*)d_ws + 32 * 1024); // 16 KB final u
    float* out = (float*)d_out;

    mha_fused<<<NB, NT, 0, stream>>>(x, wv, bv, fcw, fcb, lng, lnb,
                                     out, xs, u, bar);
}